// Round 15
// baseline (138.619 us; speedup 1.0000x reference)
//
#include <hip/hip_runtime.h>
#include <hip/hip_bf16.h>
#include <stdint.h>

typedef __hip_bfloat16 bf16;
typedef __attribute__((ext_vector_type(8))) short short8;
typedef __attribute__((ext_vector_type(4))) float f32x4;
typedef __attribute__((ext_vector_type(16))) float f32x16;

#define MFMA16(A, B, C) __builtin_amdgcn_mfma_f32_16x16x32_bf16(A, B, C, 0, 0, 0)
#define MFMA32(A, B, C) __builtin_amdgcn_mfma_f32_32x32x16_bf16(A, B, C, 0, 0, 0)

// ---- constants ----
#define SB 2
#define SS 2048
#define SD 768
#define SH 12
#define SM (SB*SS)            // 4096 rows
#define BHSD (SB*SH*SS*64)    // 3145728 elems per Q/K/V
// (1/sqrt(64)) * log2(e) folded into Q at projection time -> attn works in exp2 domain
#define QSCALE 0.18033688011112042f

__device__ __forceinline__ void gload_lds16(const bf16* g, bf16* l) {
    __builtin_amdgcn_global_load_lds(
        (const __attribute__((address_space(1))) void*)(g),
        (__attribute__((address_space(3))) void*)(l),
        16, 0, 0);
}

#define BARSYNC() do { \
    asm volatile("s_waitcnt vmcnt(0)" ::: "memory"); \
    __builtin_amdgcn_s_barrier(); \
    __builtin_amdgcn_sched_barrier(0); \
} while (0)

// f32 pair -> packed bf16 (lo=a, hi=b)
__device__ __forceinline__ int cvtpk(float a, float b) {
    int r;
    asm("v_cvt_pk_bf16_f32 %0, %1, %2" : "=v"(r) : "v"(a), "v"(b));
    return r;
}
// a's lanes 32-63 <-> b's lanes 0-31
__device__ __forceinline__ void plswap(int& a, int& b) {
    asm("v_permlane32_swap_b32 %0, %1" : "+v"(a), "+v"(b));
}

// ---- fused f32 -> bf16 convert for x + 4 weights ----
__global__ void cvt_all(const float4* __restrict__ x,  const float4* __restrict__ w0,
                        const float4* __restrict__ w1, const float4* __restrict__ w2,
                        const float4* __restrict__ w3,
                        uint64_t* __restrict__ xb, uint64_t* __restrict__ wqkv,
                        uint64_t* __restrict__ wob) {
    int bid = blockIdx.x;
    const float4* s; uint64_t* d; int base;
    if (bid < 3072) { s = x; d = xb; base = bid << 8; }
    else {
        int t = bid - 3072, seg = t / 576, li = t - seg * 576;
        s = (seg == 0) ? w0 : (seg == 1) ? w1 : (seg == 2) ? w2 : w3;
        d = (seg < 3) ? (wqkv + seg * 147456) : wob;
        base = li << 8;
    }
    int i = base + threadIdx.x;
    float4 v = s[i];
    union { bf16 h[4]; uint64_t u; } p;
    p.h[0] = __float2bfloat16(v.x);
    p.h[1] = __float2bfloat16(v.y);
    p.h[2] = __float2bfloat16(v.z);
    p.h[3] = __float2bfloat16(v.w);
    d[i] = p.u;
}

// ---- MFMA GEMM: Y = A[M,K] @ Bw[N,K]^T, 128x128 tile, BK=64 ----
template<int EPI>
__global__ __launch_bounds__(256) void gemm_bt(const bf16* __restrict__ A,
                                               const bf16* __restrict__ Bw,
                                               void* __restrict__ Out,
                                               int K) {
    __shared__ bf16 lA[128 * 64];
    __shared__ bf16 lB[128 * 64];
    const int tid  = threadIdx.x;
    const int lane = tid & 63;
    const int wid  = tid >> 6;
    const int wr = wid >> 1, wc = wid & 1;
    const int m0 = blockIdx.y * 128, n0 = blockIdx.x * 128;
    const int g = lane >> 4, l15 = lane & 15;
    const int srow = lane >> 3, slot = lane & 7;

    f32x4 acc[4][4] = {};

    for (int kt = 0; kt < K; kt += 64) {
        __syncthreads();
        #pragma unroll
        for (int p = 0; p < 4; ++p) {
            int c = wid * 4 + p;
            int row = c * 8 + srow;
            int colsw = (slot ^ (row & 7)) * 8;
            gload_lds16(A  + (m0 + row) * K + kt + colsw, &lA[c * 512]);
            gload_lds16(Bw + (n0 + row) * K + kt + colsw, &lB[c * 512]);
        }
        __syncthreads();
        #pragma unroll
        for (int ks = 0; ks < 2; ++ks) {
            short8 af[4], bfv[4];
            #pragma unroll
            for (int m = 0; m < 4; ++m) {
                int row = wr * 64 + m * 16 + l15;
                int idx = row * 64 + (((ks * 4 + g) ^ (row & 7)) * 8);
                af[m] = *reinterpret_cast<const short8*>(&lA[idx]);
            }
            #pragma unroll
            for (int n = 0; n < 4; ++n) {
                int row = wc * 64 + n * 16 + l15;
                int idx = row * 64 + (((ks * 4 + g) ^ (row & 7)) * 8);
                bfv[n] = *reinterpret_cast<const short8*>(&lB[idx]);
            }
            #pragma unroll
            for (int m = 0; m < 4; ++m)
                #pragma unroll
                for (int n = 0; n < 4; ++n)
                    acc[m][n] = MFMA16(af[m], bfv[n], acc[m][n]);
        }
    }

    #pragma unroll
    for (int m = 0; m < 4; ++m) {
        #pragma unroll
        for (int n = 0; n < 4; ++n) {
            int col = n0 + wc * 64 + n * 16 + l15;
            #pragma unroll
            for (int r = 0; r < 4; ++r) {
                int row = m0 + wr * 64 + m * 16 + g * 4 + r;
                float v = acc[m][n][r];
                if constexpr (EPI == 0) {
                    int which = (col >= 1536) ? 2 : (col >= 768 ? 1 : 0);
                    int e = col - which * 768;
                    int h = e >> 6, d = e & 63;
                    int b = row >> 11, s = row & 2047;
                    int bh = b * SH + h;
                    bf16* dst = (bf16*)Out;
                    int idx;
                    if (which == 2) idx = 2 * BHSD + (bh * 64 + d) * SS + s;   // V^T [bh][dk][s]
                    else            idx = which * BHSD + (bh * SS + s) * 64 + d;
                    if (which == 0) v *= QSCALE;
                    dst[idx] = __float2bfloat16(v);
                } else {
                    ((float*)Out)[row * SD + col] = v;
                }
            }
        }
    }
}

// ---- flash attention: shared-LDS 4-wave blocks, split-K, exp2-direct ----
// R15: finer work units (chunk = 4 pair-steps) -> 1728 blocks (6.75/CU vs
// the 5/CU LDS cap, so LDS is the binder, not the grid) + heavy-first
// dispatch order (large qg at low blockIdx) to kill the heavy-block tail.
// Compute body / staging / swizzle / atomic epilogue identical to R14.
__global__ __launch_bounds__(256) void attn_kernel(const bf16* __restrict__ Qb,
                                                   const bf16* __restrict__ Kb,
                                                   const bf16* __restrict__ Vtb,
                                                   float* __restrict__ Op,
                                                   float* __restrict__ lp) {
    __shared__ bf16 lK[2][4096];   // [kv 64][d 64], swizzled
    __shared__ bf16 lV[2][4096];   // [d 64][kv 64], swizzled

    const int bid = blockIdx.x;              // 0..1727
    const int xcd = bid & 7, li = bid >> 3;  // li 0..215
    const int g72 = li / 72;                 // 0..2
    const int bh = xcd * 3 + g72;
    const int t = 71 - (li - g72 * 72);      // heavy-first: t=71 -> qg=15 first

    // decode t -> (qg, ck); chunks per group C(qg) = (qg>>1)+1, chunk = 4 pairs
    // cumulative over group-pairs g2: units before g2 = g2*(g2+1)
    int g2 = 0;
    while ((g2 + 1) * (g2 + 2) <= t) ++g2;           // <= 8 scalar iters
    int rem = t - g2 * (g2 + 1);
    int qg = 2 * g2 + (rem >= g2 + 1 ? 1 : 0);
    int ck = (rem >= g2 + 1) ? (rem - (g2 + 1)) : rem;

    const int tid = threadIdx.x, lane = tid & 63, w = tid >> 6;
    const int l31 = lane & 31, hi = lane >> 5;
    const int srow = lane >> 3, slot = lane & 7;

    const int j  = qg * 4 + w;            // this wave's q-tile (32 rows)
    const int jp = 2 * qg + (w >> 1);     // wave's last pair-step
    const int p0 = ck * 4;
    const int pe_ = 2 * qg + 1;
    const int pe = (p0 + 3 < pe_) ? (p0 + 3) : pe_;   // block chunk end

    const bf16* Qh = Qb + bh * SS * 64;
    const bf16* Kh = Kb + bh * SS * 64;
    const bf16* Vh = Vtb + bh * 64 * SS;

    const int qself = j * 32 + l31;
    short8 qf[4];
    #pragma unroll
    for (int ks = 0; ks < 4; ++ks)
        qf[ks] = *reinterpret_cast<const short8*>(Qh + qself * 64 + ks * 16 + hi * 8);

    f32x16 oacc[2];
    #pragma unroll
    for (int n = 0; n < 2; ++n)
        #pragma unroll
        for (int r = 0; r < 16; ++r) oacc[n][r] = 0.f;
    float lrow = 0.f;

    // R6-verified cooperative staging: 4 waves cover 8 chunks of K + V
    auto STAGE = [&](int buf, int kt) {
        #pragma unroll
        for (int p = 0; p < 2; ++p) {
            int c = w * 2 + p;                   // chunk 0..7, 8 rows each
            int row = c * 8 + srow;
            int colsw = (slot ^ (row & 7)) * 8;
            gload_lds16(Kh + (kt * 64 + row) * 64 + colsw, &lK[buf][c * 512]);
            gload_lds16(Vh + row * SS + kt * 64 + colsw, &lV[buf][c * 512]);
        }
    };

    STAGE(0, p0);
    BARSYNC();

    int cur = 0;
    for (int pt = p0; pt <= pe; ++pt) {
        if (pt < pe) STAGE(cur ^ 1, pt + 1);

        if (pt <= jp) {
            const int T0 = 2 * pt, T1 = T0 + 1;
            f32x16 s0_, s1_;
            #pragma unroll
            for (int r = 0; r < 16; ++r) { s0_[r] = 0.f; s1_[r] = 0.f; }

            __builtin_amdgcn_s_setprio(1);
            #pragma unroll
            for (int ks = 0; ks < 4; ++ks) {
                int row0 = l31;
                int idx0 = row0 * 64 + (((2 * ks + hi) ^ (row0 & 7)) * 8);
                short8 kf0 = *reinterpret_cast<const short8*>(&lK[cur][idx0]);
                s0_ = MFMA32(kf0, qf[ks], s0_);
                int row1 = 32 + l31;
                int idx1 = row1 * 64 + (((2 * ks + hi) ^ (row1 & 7)) * 8);
                short8 kf1 = *reinterpret_cast<const short8*>(&lK[cur][idx1]);
                s1_ = MFMA32(kf1, qf[ks], s1_);
            }
            __builtin_amdgcn_s_setprio(0);

            if (T0 == j) {
                #pragma unroll
                for (int r = 0; r < 16; ++r) {
                    int kvrow = (r & 3) + 8 * (r >> 2) + 4 * hi;
                    if (kvrow > l31) s0_[r] = -1e30f;
                }
            }
            if (T1 == j) {
                #pragma unroll
                for (int r = 0; r < 16; ++r) {
                    int kvrow = (r & 3) + 8 * (r >> 2) + 4 * hi;
                    if (kvrow > l31) s1_[r] = -1e30f;
                }
            } else if (T1 > j) {
                #pragma unroll
                for (int r = 0; r < 16; ++r) s1_[r] = -1e30f;
            }

            // exp2-direct (R11): shift cancels in O'/l'
            #pragma unroll
            for (int r = 0; r < 16; ++r) {
                s0_[r] = exp2f(s0_[r]);
                s1_[r] = exp2f(s1_[r]);
            }
            float w0 = ((s0_[0] + s0_[1]) + (s0_[2] + s0_[3]))
                     + ((s0_[4] + s0_[5]) + (s0_[6] + s0_[7]));
            float w1 = ((s0_[8] + s0_[9]) + (s0_[10] + s0_[11]))
                     + ((s0_[12] + s0_[13]) + (s0_[14] + s0_[15]));
            float w2 = ((s1_[0] + s1_[1]) + (s1_[2] + s1_[3]))
                     + ((s1_[4] + s1_[5]) + (s1_[6] + s1_[7]));
            float w3 = ((s1_[8] + s1_[9]) + (s1_[10] + s1_[11]))
                     + ((s1_[12] + s1_[13]) + (s1_[14] + s1_[15]));
            lrow += (w0 + w1) + (w2 + w3);

            // P -> bf16 fragments (R11-verified cvtpk + plswap)
            int a0 = cvtpk(s0_[0],  s0_[1]),  a1 = cvtpk(s0_[2],  s0_[3]);
            int b0 = cvtpk(s0_[4],  s0_[5]),  b1 = cvtpk(s0_[6],  s0_[7]);
            plswap(a0, b0); plswap(a1, b1);
            int a2 = cvtpk(s0_[8],  s0_[9]),  a3 = cvtpk(s0_[10], s0_[11]);
            int b2 = cvtpk(s0_[12], s0_[13]), b3 = cvtpk(s0_[14], s0_[15]);
            plswap(a2, b2); plswap(a3, b3);
            int c0 = cvtpk(s1_[0],  s1_[1]),  c1 = cvtpk(s1_[2],  s1_[3]);
            int d0 = cvtpk(s1_[4],  s1_[5]),  d1 = cvtpk(s1_[6],  s1_[7]);
            plswap(c0, d0); plswap(c1, d1);
            int c2 = cvtpk(s1_[8],  s1_[9]),  c3 = cvtpk(s1_[10], s1_[11]);
            int d2 = cvtpk(s1_[12], s1_[13]), d3 = cvtpk(s1_[14], s1_[15]);
            plswap(c2, d2); plswap(c3, d3);
            union { int wd[4]; short8 s8; } u0_, u1_, u2_, u3_;
            u0_.wd[0] = a0; u0_.wd[1] = a1; u0_.wd[2] = b0; u0_.wd[3] = b1;
            u1_.wd[0] = a2; u1_.wd[1] = a3; u1_.wd[2] = b2; u1_.wd[3] = b3;
            u2_.wd[0] = c0; u2_.wd[1] = c1; u2_.wd[2] = d0; u2_.wd[3] = d1;
            u3_.wd[0] = c2; u3_.wd[1] = c3; u3_.wd[2] = d2; u3_.wd[3] = d3;

            // O += P @ V from LDS (R6-verified idx: slot = 4t + 2ks + hi)
            __builtin_amdgcn_s_setprio(1);
            #pragma unroll
            for (int n = 0; n < 2; ++n) {
                int rowv = n * 32 + l31;
                int base = rowv * 64;
                int sw = rowv & 7;
                short8 vf0 = *reinterpret_cast<const short8*>(&lV[cur][base + (((0 + hi) ^ sw) * 8)]);
                oacc[n] = MFMA32(u0_.s8, vf0, oacc[n]);
                short8 vf1 = *reinterpret_cast<const short8*>(&lV[cur][base + (((2 + hi) ^ sw) * 8)]);
                oacc[n] = MFMA32(u1_.s8, vf1, oacc[n]);
                short8 vf2 = *reinterpret_cast<const short8*>(&lV[cur][base + (((4 + hi) ^ sw) * 8)]);
                oacc[n] = MFMA32(u2_.s8, vf2, oacc[n]);
                short8 vf3 = *reinterpret_cast<const short8*>(&lV[cur][base + (((6 + hi) ^ sw) * 8)]);
                oacc[n] = MFMA32(u3_.s8, vf3, oacc[n]);
            }
            __builtin_amdgcn_s_setprio(0);
        }

        BARSYNC();
        cur ^= 1;
    }

    // ---- epilogue: atomically accumulate partial (O', l') (R12-verified) ----
    const int qrow0 = bh * SS + j * 32;
    atomicAdd(&lp[qrow0 + l31], lrow);
    #pragma unroll
    for (int n = 0; n < 2; ++n) {
        #pragma unroll
        for (int r = 0; r < 16; ++r) {
            int q = (r & 3) + 8 * (r >> 2) + 4 * hi;
            int d = n * 32 + l31;
            atomicAdd(&Op[(qrow0 + q) * 64 + d], oacc[n][r]);
        }
    }
}

// ---- normalize: AO[b,s,h*64+d] = Op[bh,s,d] / lp[bh,s] ----
__global__ __launch_bounds__(256) void norm_kernel(const float* __restrict__ Op,
                                                   const float* __restrict__ lp,
                                                   bf16* __restrict__ AO) {
    int idx = blockIdx.x * 256 + threadIdx.x;     // 0 .. 3145727
    int d = idx & 63, srow = idx >> 6;            // srow = bh*2048 + s
    int bh = srow >> 11, s = srow & 2047;
    int b = bh / SH, h = bh - b * SH;
    float v = Op[idx] / lp[srow];
    AO[(b * SS + s) * SD + h * 64 + d] = __float2bfloat16(v);
}

extern "C" void kernel_launch(void* const* d_in, const int* in_sizes, int n_in,
                              void* d_out, int out_size, void* d_ws, size_t ws_size,
                              hipStream_t stream) {
    const float* x  = (const float*)d_in[0];
    const float* wq = (const float*)d_in[1];
    const float* wk = (const float*)d_in[2];
    const float* wv = (const float*)d_in[3];
    const float* wo = (const float*)d_in[4];
    float* out = (float*)d_out;

    bf16* xb   = (bf16*)d_ws;              // reused as ao after gemm<0>
    bf16* wqkv = xb + SM * SD;
    bf16* wob  = wqkv + 3 * SD * SD;
    bf16* qkv  = wob + SD * SD;            // Q, K, V^T
    float* Op  = (float*)(qkv + 3 * BHSD); // 3,145,728 f32 partial O'
    float* lp  = Op + 3145728;             // 49,152 f32
    bf16* ao   = xb;

    hipMemsetAsync(Op, 0, (3145728 + SB * SH * SS) * sizeof(float), stream);

    cvt_all<<<3072 + 4 * 576, 256, 0, stream>>>(
        (const float4*)x, (const float4*)wq, (const float4*)wk,
        (const float4*)wv, (const float4*)wo,
        (uint64_t*)xb, (uint64_t*)wqkv, (uint64_t*)wob);

    gemm_bt<0><<<dim3(2304 / 128, SM / 128), 256, 0, stream>>>(xb, wqkv, (void*)qkv, SD);
    attn_kernel<<<1728, 256, 0, stream>>>(qkv, qkv + BHSD, qkv + 2 * BHSD, Op, lp);
    norm_kernel<<<3145728 / 256, 256, 0, stream>>>(Op, lp, ao);
    gemm_bt<1><<<dim3(SD / 128, SM / 128), 256, 0, stream>>>(ao, wob, (void*)out, SD);
}

// Round 16
// 122.494 us; speedup vs baseline: 1.1316x; 1.1316x over previous
//
#include <hip/hip_runtime.h>
#include <hip/hip_bf16.h>
#include <stdint.h>

typedef __hip_bfloat16 bf16;
typedef __attribute__((ext_vector_type(8))) short short8;
typedef __attribute__((ext_vector_type(4))) float f32x4;
typedef __attribute__((ext_vector_type(16))) float f32x16;

#define MFMA16(A, B, C) __builtin_amdgcn_mfma_f32_16x16x32_bf16(A, B, C, 0, 0, 0)
#define MFMA32(A, B, C) __builtin_amdgcn_mfma_f32_32x32x16_bf16(A, B, C, 0, 0, 0)

// ---- constants ----
#define SB 2
#define SS 2048
#define SD 768
#define SH 12
#define SM (SB*SS)            // 4096 rows
#define BHSD (SB*SH*SS*64)    // 3145728 elems per Q/K/V
// (1/sqrt(64)) * log2(e) folded into Q at projection time -> attn works in exp2 domain
#define QSCALE 0.18033688011112042f

__device__ __forceinline__ void gload_lds16(const bf16* g, bf16* l) {
    __builtin_amdgcn_global_load_lds(
        (const __attribute__((address_space(1))) void*)(g),
        (__attribute__((address_space(3))) void*)(l),
        16, 0, 0);
}

// f32 pair -> packed bf16 (lo=a, hi=b)
__device__ __forceinline__ int cvtpk(float a, float b) {
    int r;
    asm("v_cvt_pk_bf16_f32 %0, %1, %2" : "=v"(r) : "v"(a), "v"(b));
    return r;
}
// a's lanes 32-63 <-> b's lanes 0-31
__device__ __forceinline__ void plswap(int& a, int& b) {
    asm("v_permlane32_swap_b32 %0, %1" : "+v"(a), "+v"(b));
}

// ---- fused f32 -> bf16 convert for x + 4 weights ----
__global__ void cvt_all(const float4* __restrict__ x,  const float4* __restrict__ w0,
                        const float4* __restrict__ w1, const float4* __restrict__ w2,
                        const float4* __restrict__ w3,
                        uint64_t* __restrict__ xb, uint64_t* __restrict__ wqkv,
                        uint64_t* __restrict__ wob) {
    int bid = blockIdx.x;
    const float4* s; uint64_t* d; int base;
    if (bid < 3072) { s = x; d = xb; base = bid << 8; }
    else {
        int t = bid - 3072, seg = t / 576, li = t - seg * 576;
        s = (seg == 0) ? w0 : (seg == 1) ? w1 : (seg == 2) ? w2 : w3;
        d = (seg < 3) ? (wqkv + seg * 147456) : wob;
        base = li << 8;
    }
    int i = base + threadIdx.x;
    float4 v = s[i];
    union { bf16 h[4]; uint64_t u; } p;
    p.h[0] = __float2bfloat16(v.x);
    p.h[1] = __float2bfloat16(v.y);
    p.h[2] = __float2bfloat16(v.z);
    p.h[3] = __float2bfloat16(v.w);
    d[i] = p.u;
}

// ---- MFMA GEMM: Y = A[M,K] @ Bw[N,K]^T, 128x128 tile, BK=64 ----
template<int EPI>
__global__ __launch_bounds__(256) void gemm_bt(const bf16* __restrict__ A,
                                               const bf16* __restrict__ Bw,
                                               void* __restrict__ Out,
                                               int K) {
    __shared__ bf16 lA[128 * 64];
    __shared__ bf16 lB[128 * 64];
    const int tid  = threadIdx.x;
    const int lane = tid & 63;
    const int wid  = tid >> 6;
    const int wr = wid >> 1, wc = wid & 1;
    const int m0 = blockIdx.y * 128, n0 = blockIdx.x * 128;
    const int g = lane >> 4, l15 = lane & 15;
    const int srow = lane >> 3, slot = lane & 7;

    f32x4 acc[4][4] = {};

    for (int kt = 0; kt < K; kt += 64) {
        __syncthreads();
        #pragma unroll
        for (int p = 0; p < 4; ++p) {
            int c = wid * 4 + p;
            int row = c * 8 + srow;
            int colsw = (slot ^ (row & 7)) * 8;
            gload_lds16(A  + (m0 + row) * K + kt + colsw, &lA[c * 512]);
            gload_lds16(Bw + (n0 + row) * K + kt + colsw, &lB[c * 512]);
        }
        __syncthreads();
        #pragma unroll
        for (int ks = 0; ks < 2; ++ks) {
            short8 af[4], bfv[4];
            #pragma unroll
            for (int m = 0; m < 4; ++m) {
                int row = wr * 64 + m * 16 + l15;
                int idx = row * 64 + (((ks * 4 + g) ^ (row & 7)) * 8);
                af[m] = *reinterpret_cast<const short8*>(&lA[idx]);
            }
            #pragma unroll
            for (int n = 0; n < 4; ++n) {
                int row = wc * 64 + n * 16 + l15;
                int idx = row * 64 + (((ks * 4 + g) ^ (row & 7)) * 8);
                bfv[n] = *reinterpret_cast<const short8*>(&lB[idx]);
            }
            #pragma unroll
            for (int m = 0; m < 4; ++m)
                #pragma unroll
                for (int n = 0; n < 4; ++n)
                    acc[m][n] = MFMA16(af[m], bfv[n], acc[m][n]);
        }
    }

    #pragma unroll
    for (int m = 0; m < 4; ++m) {
        #pragma unroll
        for (int n = 0; n < 4; ++n) {
            int col = n0 + wc * 64 + n * 16 + l15;
            #pragma unroll
            for (int r = 0; r < 4; ++r) {
                int row = m0 + wr * 64 + m * 16 + g * 4 + r;
                float v = acc[m][n][r];
                if constexpr (EPI == 0) {
                    int which = (col >= 1536) ? 2 : (col >= 768 ? 1 : 0);
                    int e = col - which * 768;
                    int h = e >> 6, d = e & 63;
                    int b = row >> 11, s = row & 2047;
                    int bh = b * SH + h;
                    bf16* dst = (bf16*)Out;
                    int idx;
                    if (which == 2) idx = 2 * BHSD + (bh * 64 + d) * SS + s;   // V^T [bh][dk][s]
                    else            idx = which * BHSD + (bh * SS + s) * 64 + d;
                    if (which == 0) v *= QSCALE;
                    dst[idx] = __float2bfloat16(v);
                } else {
                    ((float*)Out)[row * SD + col] = v;
                }
            }
        }
    }
}

// ---- flash attention: shared-LDS 4-wave blocks, split-K, exp2-direct ----
// R16 = R14 geometry (chunk=8 pair-steps, 40 units/bh, 960 blocks) with:
//  (1) counted vmcnt(4) across the barrier (T4): STAGE(next) -> vmcnt(4) ->
//      barrier -> compute -> barrier. Next-tile loads stay in flight under
//      compute instead of draining cold every step.
//  (2) heavy-first dispatch (39-u) so 8-step chunks launch first.
// Compute body / staging / swizzle / atomic epilogue identical to R14.
__global__ __launch_bounds__(256) void attn_kernel(const bf16* __restrict__ Qb,
                                                   const bf16* __restrict__ Kb,
                                                   const bf16* __restrict__ Vtb,
                                                   float* __restrict__ Op,
                                                   float* __restrict__ lp) {
    __shared__ bf16 lK[2][4096];   // [kv 64][d 64], swizzled
    __shared__ bf16 lV[2][4096];   // [d 64][kv 64], swizzled

    const int bid = blockIdx.x;              // 0..959
    const int xcd = bid & 7, li = bid >> 3;  // li 0..119
    const int g40 = li / 40;                 // 0..2
    const int bh = xcd * 3 + g40;
    const int u = 39 - (li - g40 * 40);      // heavy-first: u=39 -> qg=15 first

    // decode unit -> (qg, ck); chunks per group = ceil((2qg+2)/8)
    int qg, ck;
    if (u < 4)       { qg = u;                           ck = 0; }
    else if (u < 12) { int t = u - 4;  qg = 4 + (t >> 1);  ck = t & 1; }
    else if (u < 24) { int t = u - 12; int q3 = t / 3; qg = 8 + q3; ck = t - 3 * q3; }
    else             { int t = u - 24; qg = 12 + (t >> 2); ck = t & 3; }

    const int tid = threadIdx.x, lane = tid & 63, w = tid >> 6;
    const int l31 = lane & 31, hi = lane >> 5;
    const int srow = lane >> 3, slot = lane & 7;

    const int j  = qg * 4 + w;            // this wave's q-tile (32 rows)
    const int jp = 2 * qg + (w >> 1);     // wave's last pair-step
    const int p0 = ck * 8;
    const int pe_ = 2 * qg + 1;
    const int pe = (p0 + 7 < pe_) ? (p0 + 7) : pe_;   // block chunk end

    const bf16* Qh = Qb + bh * SS * 64;
    const bf16* Kh = Kb + bh * SS * 64;
    const bf16* Vh = Vtb + bh * 64 * SS;

    const int qself = j * 32 + l31;
    short8 qf[4];
    #pragma unroll
    for (int ks = 0; ks < 4; ++ks)
        qf[ks] = *reinterpret_cast<const short8*>(Qh + qself * 64 + ks * 16 + hi * 8);

    f32x16 oacc[2];
    #pragma unroll
    for (int n = 0; n < 2; ++n)
        #pragma unroll
        for (int r = 0; r < 16; ++r) oacc[n][r] = 0.f;
    float lrow = 0.f;

    // R6-verified cooperative staging: 4 waves cover 8 chunks of K + V
    // (4 gload_lds per wave per tile -> vmcnt granularity = 4)
    auto STAGE = [&](int buf, int kt) {
        #pragma unroll
        for (int p = 0; p < 2; ++p) {
            int c = w * 2 + p;                   // chunk 0..7, 8 rows each
            int row = c * 8 + srow;
            int colsw = (slot ^ (row & 7)) * 8;
            gload_lds16(Kh + (kt * 64 + row) * 64 + colsw, &lK[buf][c * 512]);
            gload_lds16(Vh + row * SS + kt * 64 + colsw, &lV[buf][c * 512]);
        }
    };

    STAGE(0, p0);

    int cur = 0;
    for (int pt = p0; pt <= pe; ++pt) {
        // issue next tile's loads; they stay in flight under this tile's compute
        if (pt < pe) {
            STAGE(cur ^ 1, pt + 1);
            asm volatile("s_waitcnt vmcnt(4)" ::: "memory");   // tile-pt loads landed
        } else {
            asm volatile("s_waitcnt vmcnt(0)" ::: "memory");
        }
        __builtin_amdgcn_sched_barrier(0);
        __builtin_amdgcn_s_barrier();          // all waves' tile-pt chunks visible
        __builtin_amdgcn_sched_barrier(0);

        if (pt <= jp) {
            const int T0 = 2 * pt, T1 = T0 + 1;
            f32x16 s0_, s1_;
            #pragma unroll
            for (int r = 0; r < 16; ++r) { s0_[r] = 0.f; s1_[r] = 0.f; }

            __builtin_amdgcn_s_setprio(1);
            #pragma unroll
            for (int ks = 0; ks < 4; ++ks) {
                int row0 = l31;
                int idx0 = row0 * 64 + (((2 * ks + hi) ^ (row0 & 7)) * 8);
                short8 kf0 = *reinterpret_cast<const short8*>(&lK[cur][idx0]);
                s0_ = MFMA32(kf0, qf[ks], s0_);
                int row1 = 32 + l31;
                int idx1 = row1 * 64 + (((2 * ks + hi) ^ (row1 & 7)) * 8);
                short8 kf1 = *reinterpret_cast<const short8*>(&lK[cur][idx1]);
                s1_ = MFMA32(kf1, qf[ks], s1_);
            }
            __builtin_amdgcn_s_setprio(0);

            if (T0 == j) {
                #pragma unroll
                for (int r = 0; r < 16; ++r) {
                    int kvrow = (r & 3) + 8 * (r >> 2) + 4 * hi;
                    if (kvrow > l31) s0_[r] = -1e30f;
                }
            }
            if (T1 == j) {
                #pragma unroll
                for (int r = 0; r < 16; ++r) {
                    int kvrow = (r & 3) + 8 * (r >> 2) + 4 * hi;
                    if (kvrow > l31) s1_[r] = -1e30f;
                }
            } else if (T1 > j) {
                #pragma unroll
                for (int r = 0; r < 16; ++r) s1_[r] = -1e30f;
            }

            // exp2-direct (R11): shift cancels in O'/l'
            #pragma unroll
            for (int r = 0; r < 16; ++r) {
                s0_[r] = exp2f(s0_[r]);
                s1_[r] = exp2f(s1_[r]);
            }
            float w0 = ((s0_[0] + s0_[1]) + (s0_[2] + s0_[3]))
                     + ((s0_[4] + s0_[5]) + (s0_[6] + s0_[7]));
            float w1 = ((s0_[8] + s0_[9]) + (s0_[10] + s0_[11]))
                     + ((s0_[12] + s0_[13]) + (s0_[14] + s0_[15]));
            float w2 = ((s1_[0] + s1_[1]) + (s1_[2] + s1_[3]))
                     + ((s1_[4] + s1_[5]) + (s1_[6] + s1_[7]));
            float w3 = ((s1_[8] + s1_[9]) + (s1_[10] + s1_[11]))
                     + ((s1_[12] + s1_[13]) + (s1_[14] + s1_[15]));
            lrow += (w0 + w1) + (w2 + w3);

            // P -> bf16 fragments (R11-verified cvtpk + plswap)
            int a0 = cvtpk(s0_[0],  s0_[1]),  a1 = cvtpk(s0_[2],  s0_[3]);
            int b0 = cvtpk(s0_[4],  s0_[5]),  b1 = cvtpk(s0_[6],  s0_[7]);
            plswap(a0, b0); plswap(a1, b1);
            int a2 = cvtpk(s0_[8],  s0_[9]),  a3 = cvtpk(s0_[10], s0_[11]);
            int b2 = cvtpk(s0_[12], s0_[13]), b3 = cvtpk(s0_[14], s0_[15]);
            plswap(a2, b2); plswap(a3, b3);
            int c0 = cvtpk(s1_[0],  s1_[1]),  c1 = cvtpk(s1_[2],  s1_[3]);
            int d0 = cvtpk(s1_[4],  s1_[5]),  d1 = cvtpk(s1_[6],  s1_[7]);
            plswap(c0, d0); plswap(c1, d1);
            int c2 = cvtpk(s1_[8],  s1_[9]),  c3 = cvtpk(s1_[10], s1_[11]);
            int d2 = cvtpk(s1_[12], s1_[13]), d3 = cvtpk(s1_[14], s1_[15]);
            plswap(c2, d2); plswap(c3, d3);
            union { int wd[4]; short8 s8; } u0_, u1_, u2_, u3_;
            u0_.wd[0] = a0; u0_.wd[1] = a1; u0_.wd[2] = b0; u0_.wd[3] = b1;
            u1_.wd[0] = a2; u1_.wd[1] = a3; u1_.wd[2] = b2; u1_.wd[3] = b3;
            u2_.wd[0] = c0; u2_.wd[1] = c1; u2_.wd[2] = d0; u2_.wd[3] = d1;
            u3_.wd[0] = c2; u3_.wd[1] = c3; u3_.wd[2] = d2; u3_.wd[3] = d3;

            // O += P @ V from LDS (R6-verified idx: slot = 4t + 2ks + hi)
            __builtin_amdgcn_s_setprio(1);
            #pragma unroll
            for (int n = 0; n < 2; ++n) {
                int rowv = n * 32 + l31;
                int base = rowv * 64;
                int sw = rowv & 7;
                short8 vf0 = *reinterpret_cast<const short8*>(&lV[cur][base + (((0 + hi) ^ sw) * 8)]);
                oacc[n] = MFMA32(u0_.s8, vf0, oacc[n]);
                short8 vf1 = *reinterpret_cast<const short8*>(&lV[cur][base + (((2 + hi) ^ sw) * 8)]);
                oacc[n] = MFMA32(u1_.s8, vf1, oacc[n]);
                short8 vf2 = *reinterpret_cast<const short8*>(&lV[cur][base + (((4 + hi) ^ sw) * 8)]);
                oacc[n] = MFMA32(u2_.s8, vf2, oacc[n]);
                short8 vf3 = *reinterpret_cast<const short8*>(&lV[cur][base + (((6 + hi) ^ sw) * 8)]);
                oacc[n] = MFMA32(u3_.s8, vf3, oacc[n]);
            }
            __builtin_amdgcn_s_setprio(0);
        }

        __builtin_amdgcn_s_barrier();   // readers done before next-iter overwrite
        cur ^= 1;
    }

    // ---- epilogue: atomically accumulate partial (O', l') (R12-verified) ----
    const int qrow0 = bh * SS + j * 32;
    atomicAdd(&lp[qrow0 + l31], lrow);
    #pragma unroll
    for (int n = 0; n < 2; ++n) {
        #pragma unroll
        for (int r = 0; r < 16; ++r) {
            int q = (r & 3) + 8 * (r >> 2) + 4 * hi;
            int d = n * 32 + l31;
            atomicAdd(&Op[(qrow0 + q) * 64 + d], oacc[n][r]);
        }
    }
}

// ---- normalize: AO[b,s,h*64+d] = Op[bh,s,d] / lp[bh,s] ----
__global__ __launch_bounds__(256) void norm_kernel(const float* __restrict__ Op,
                                                   const float* __restrict__ lp,
                                                   bf16* __restrict__ AO) {
    int idx = blockIdx.x * 256 + threadIdx.x;     // 0 .. 3145727
    int d = idx & 63, srow = idx >> 6;            // srow = bh*2048 + s
    int bh = srow >> 11, s = srow & 2047;
    int b = bh / SH, h = bh - b * SH;
    float v = Op[idx] / lp[srow];
    AO[(b * SS + s) * SD + h * 64 + d] = __float2bfloat16(v);
}

extern "C" void kernel_launch(void* const* d_in, const int* in_sizes, int n_in,
                              void* d_out, int out_size, void* d_ws, size_t ws_size,
                              hipStream_t stream) {
    const float* x  = (const float*)d_in[0];
    const float* wq = (const float*)d_in[1];
    const float* wk = (const float*)d_in[2];
    const float* wv = (const float*)d_in[3];
    const float* wo = (const float*)d_in[4];
    float* out = (float*)d_out;

    bf16* xb   = (bf16*)d_ws;              // reused as ao after gemm<0>
    bf16* wqkv = xb + SM * SD;
    bf16* wob  = wqkv + 3 * SD * SD;
    bf16* qkv  = wob + SD * SD;            // Q, K, V^T
    float* Op  = (float*)(qkv + 3 * BHSD); // 3,145,728 f32 partial O'
    float* lp  = Op + 3145728;             // 49,152 f32
    bf16* ao   = xb;

    hipMemsetAsync(Op, 0, (3145728 + SB * SH * SS) * sizeof(float), stream);

    cvt_all<<<3072 + 4 * 576, 256, 0, stream>>>(
        (const float4*)x, (const float4*)wq, (const float4*)wk,
        (const float4*)wv, (const float4*)wo,
        (uint64_t*)xb, (uint64_t*)wqkv, (uint64_t*)wob);

    gemm_bt<0><<<dim3(2304 / 128, SM / 128), 256, 0, stream>>>(xb, wqkv, (void*)qkv, SD);
    attn_kernel<<<960, 256, 0, stream>>>(qkv, qkv + BHSD, qkv + 2 * BHSD, Op, lp);
    norm_kernel<<<3145728 / 256, 256, 0, stream>>>(Op, lp, ao);
    gemm_bt<1><<<dim3(SD / 128, SM / 128), 256, 0, stream>>>(ao, wob, (void*)out, SD);
}

// Round 17
// 118.321 us; speedup vs baseline: 1.1715x; 1.0353x over previous
//
#include <hip/hip_runtime.h>
#include <hip/hip_bf16.h>
#include <stdint.h>

typedef __hip_bfloat16 bf16;
typedef __attribute__((ext_vector_type(8))) short short8;
typedef __attribute__((ext_vector_type(4))) float f32x4;
typedef __attribute__((ext_vector_type(16))) float f32x16;

#define MFMA16(A, B, C) __builtin_amdgcn_mfma_f32_16x16x32_bf16(A, B, C, 0, 0, 0)
#define MFMA32(A, B, C) __builtin_amdgcn_mfma_f32_32x32x16_bf16(A, B, C, 0, 0, 0)

// ---- constants ----
#define SB 2
#define SS 2048
#define SD 768
#define SH 12
#define SM (SB*SS)            // 4096 rows
#define BHSD (SB*SH*SS*64)    // 3145728 elems per Q/K/V
// (1/sqrt(64)) * log2(e) folded into Q at projection time -> attn works in exp2 domain
#define QSCALE 0.18033688011112042f

__device__ __forceinline__ void gload_lds16(const bf16* g, bf16* l) {
    __builtin_amdgcn_global_load_lds(
        (const __attribute__((address_space(1))) void*)(g),
        (__attribute__((address_space(3))) void*)(l),
        16, 0, 0);
}

// f32 pair -> packed bf16 (lo=a, hi=b)
__device__ __forceinline__ int cvtpk(float a, float b) {
    int r;
    asm("v_cvt_pk_bf16_f32 %0, %1, %2" : "=v"(r) : "v"(a), "v"(b));
    return r;
}
// a's lanes 32-63 <-> b's lanes 0-31
__device__ __forceinline__ void plswap(int& a, int& b) {
    asm("v_permlane32_swap_b32 %0, %1" : "+v"(a), "+v"(b));
}

// ---- fused f32 -> bf16 convert for x + 4 weights ----
__global__ void cvt_all(const float4* __restrict__ x,  const float4* __restrict__ w0,
                        const float4* __restrict__ w1, const float4* __restrict__ w2,
                        const float4* __restrict__ w3,
                        uint64_t* __restrict__ xb, uint64_t* __restrict__ wqkv,
                        uint64_t* __restrict__ wob) {
    int bid = blockIdx.x;
    const float4* s; uint64_t* d; int base;
    if (bid < 3072) { s = x; d = xb; base = bid << 8; }
    else {
        int t = bid - 3072, seg = t / 576, li = t - seg * 576;
        s = (seg == 0) ? w0 : (seg == 1) ? w1 : (seg == 2) ? w2 : w3;
        d = (seg < 3) ? (wqkv + seg * 147456) : wob;
        base = li << 8;
    }
    int i = base + threadIdx.x;
    float4 v = s[i];
    union { bf16 h[4]; uint64_t u; } p;
    p.h[0] = __float2bfloat16(v.x);
    p.h[1] = __float2bfloat16(v.y);
    p.h[2] = __float2bfloat16(v.z);
    p.h[3] = __float2bfloat16(v.w);
    d[i] = p.u;
}

// ---- MFMA GEMM: Y = A[M,K] @ Bw[N,K]^T, 128x128 tile, BK=64 ----
template<int EPI>
__global__ __launch_bounds__(256) void gemm_bt(const bf16* __restrict__ A,
                                               const bf16* __restrict__ Bw,
                                               void* __restrict__ Out,
                                               int K) {
    __shared__ bf16 lA[128 * 64];
    __shared__ bf16 lB[128 * 64];
    const int tid  = threadIdx.x;
    const int lane = tid & 63;
    const int wid  = tid >> 6;
    const int wr = wid >> 1, wc = wid & 1;
    const int m0 = blockIdx.y * 128, n0 = blockIdx.x * 128;
    const int g = lane >> 4, l15 = lane & 15;
    const int srow = lane >> 3, slot = lane & 7;

    f32x4 acc[4][4] = {};

    for (int kt = 0; kt < K; kt += 64) {
        __syncthreads();
        #pragma unroll
        for (int p = 0; p < 4; ++p) {
            int c = wid * 4 + p;
            int row = c * 8 + srow;
            int colsw = (slot ^ (row & 7)) * 8;
            gload_lds16(A  + (m0 + row) * K + kt + colsw, &lA[c * 512]);
            gload_lds16(Bw + (n0 + row) * K + kt + colsw, &lB[c * 512]);
        }
        __syncthreads();
        #pragma unroll
        for (int ks = 0; ks < 2; ++ks) {
            short8 af[4], bfv[4];
            #pragma unroll
            for (int m = 0; m < 4; ++m) {
                int row = wr * 64 + m * 16 + l15;
                int idx = row * 64 + (((ks * 4 + g) ^ (row & 7)) * 8);
                af[m] = *reinterpret_cast<const short8*>(&lA[idx]);
            }
            #pragma unroll
            for (int n = 0; n < 4; ++n) {
                int row = wc * 64 + n * 16 + l15;
                int idx = row * 64 + (((ks * 4 + g) ^ (row & 7)) * 8);
                bfv[n] = *reinterpret_cast<const short8*>(&lB[idx]);
            }
            #pragma unroll
            for (int m = 0; m < 4; ++m)
                #pragma unroll
                for (int n = 0; n < 4; ++n)
                    acc[m][n] = MFMA16(af[m], bfv[n], acc[m][n]);
        }
    }

    #pragma unroll
    for (int m = 0; m < 4; ++m) {
        #pragma unroll
        for (int n = 0; n < 4; ++n) {
            int col = n0 + wc * 64 + n * 16 + l15;
            #pragma unroll
            for (int r = 0; r < 4; ++r) {
                int row = m0 + wr * 64 + m * 16 + g * 4 + r;
                float v = acc[m][n][r];
                if constexpr (EPI == 0) {
                    int which = (col >= 1536) ? 2 : (col >= 768 ? 1 : 0);
                    int e = col - which * 768;
                    int h = e >> 6, d = e & 63;
                    int b = row >> 11, s = row & 2047;
                    int bh = b * SH + h;
                    bf16* dst = (bf16*)Out;
                    int idx;
                    if (which == 2) idx = 2 * BHSD + (bh * 64 + d) * SS + s;   // V^T [bh][dk][s]
                    else            idx = which * BHSD + (bh * SS + s) * 64 + d;
                    if (which == 0) v *= QSCALE;
                    dst[idx] = __float2bfloat16(v);
                } else {
                    ((float*)Out)[row * SD + col] = v;
                }
            }
        }
    }
}

// ---- flash attention: shared-LDS 4-wave blocks, split-K, exp2-direct ----
// R17 = R16 geometry/staging with a REGISTER-REDUCTION package:
//  (1) the two 32-kv sub-tiles run SEQUENTIALLY through ONE shared s_/frag
//      register set (peak live regs drop by ~16-32; TLP replaces ILP),
//  (2) __launch_bounds__(256, 4) pins the allocator to <=128 unified regs
//      -> 16 waves/CU (4 blocks) instead of the ~8 that capped R13-R16,
//  (3) wave skips its beyond-diagonal half-tile (T1 > j) outright.
// Decode / staging / swizzle / vmcnt / atomic epilogue identical to R16.
__global__ __launch_bounds__(256, 4) void attn_kernel(const bf16* __restrict__ Qb,
                                                      const bf16* __restrict__ Kb,
                                                      const bf16* __restrict__ Vtb,
                                                      float* __restrict__ Op,
                                                      float* __restrict__ lp) {
    __shared__ bf16 lK[2][4096];   // [kv 64][d 64], swizzled
    __shared__ bf16 lV[2][4096];   // [d 64][kv 64], swizzled

    const int bid = blockIdx.x;              // 0..959
    const int xcd = bid & 7, li = bid >> 3;  // li 0..119
    const int g40 = li / 40;                 // 0..2
    const int bh = xcd * 3 + g40;
    const int u = 39 - (li - g40 * 40);      // heavy-first: u=39 -> qg=15 first

    // decode unit -> (qg, ck); chunks per group = ceil((2qg+2)/8)
    int qg, ck;
    if (u < 4)       { qg = u;                           ck = 0; }
    else if (u < 12) { int t = u - 4;  qg = 4 + (t >> 1);  ck = t & 1; }
    else if (u < 24) { int t = u - 12; int q3 = t / 3; qg = 8 + q3; ck = t - 3 * q3; }
    else             { int t = u - 24; qg = 12 + (t >> 2); ck = t & 3; }

    const int tid = threadIdx.x, lane = tid & 63, w = tid >> 6;
    const int l31 = lane & 31, hi = lane >> 5;
    const int srow = lane >> 3, slot = lane & 7;

    const int j  = qg * 4 + w;            // this wave's q-tile (32 rows)
    const int jp = 2 * qg + (w >> 1);     // wave's last pair-step
    const int p0 = ck * 8;
    const int pe_ = 2 * qg + 1;
    const int pe = (p0 + 7 < pe_) ? (p0 + 7) : pe_;   // block chunk end

    const bf16* Qh = Qb + bh * SS * 64;
    const bf16* Kh = Kb + bh * SS * 64;
    const bf16* Vh = Vtb + bh * 64 * SS;

    const int qself = j * 32 + l31;
    short8 qf[4];
    #pragma unroll
    for (int ks = 0; ks < 4; ++ks)
        qf[ks] = *reinterpret_cast<const short8*>(Qh + qself * 64 + ks * 16 + hi * 8);

    f32x16 oacc[2];
    #pragma unroll
    for (int n = 0; n < 2; ++n)
        #pragma unroll
        for (int r = 0; r < 16; ++r) oacc[n][r] = 0.f;
    float lrow = 0.f;

    // R6-verified cooperative staging: 4 waves cover 8 chunks of K + V
    auto STAGE = [&](int buf, int kt) {
        #pragma unroll
        for (int p = 0; p < 2; ++p) {
            int c = w * 2 + p;                   // chunk 0..7, 8 rows each
            int row = c * 8 + srow;
            int colsw = (slot ^ (row & 7)) * 8;
            gload_lds16(Kh + (kt * 64 + row) * 64 + colsw, &lK[buf][c * 512]);
            gload_lds16(Vh + row * SS + kt * 64 + colsw, &lV[buf][c * 512]);
        }
    };

    // one 32-kv half-tile: T = kv-tile index (32 cols), h = half (0/1)
    auto HALF = [&](int cur, int T, int h) {
        f32x16 s_;
        #pragma unroll
        for (int r = 0; r < 16; ++r) s_[r] = 0.f;

        __builtin_amdgcn_s_setprio(1);
        #pragma unroll
        for (int ks = 0; ks < 4; ++ks) {
            int row = h * 32 + l31;
            int idx = row * 64 + (((2 * ks + hi) ^ (row & 7)) * 8);
            short8 kf = *reinterpret_cast<const short8*>(&lK[cur][idx]);
            s_ = MFMA32(kf, qf[ks], s_);
        }
        __builtin_amdgcn_s_setprio(0);

        if (T == j) {   // diagonal: causal mask
            #pragma unroll
            for (int r = 0; r < 16; ++r) {
                int kvrow = (r & 3) + 8 * (r >> 2) + 4 * hi;
                if (kvrow > l31) s_[r] = -1e30f;
            }
        }

        // exp2-direct (R11): shift cancels in O'/l'
        #pragma unroll
        for (int r = 0; r < 16; ++r) s_[r] = exp2f(s_[r]);
        float w0 = ((s_[0] + s_[1]) + (s_[2] + s_[3]))
                 + ((s_[4] + s_[5]) + (s_[6] + s_[7]));
        float w1 = ((s_[8] + s_[9]) + (s_[10] + s_[11]))
                 + ((s_[12] + s_[13]) + (s_[14] + s_[15]));
        lrow += (w0 + w1);

        // P -> bf16 fragments (R11-verified cvtpk + plswap)
        int a0 = cvtpk(s_[0],  s_[1]),  a1 = cvtpk(s_[2],  s_[3]);
        int b0 = cvtpk(s_[4],  s_[5]),  b1 = cvtpk(s_[6],  s_[7]);
        plswap(a0, b0); plswap(a1, b1);
        int a2 = cvtpk(s_[8],  s_[9]),  a3 = cvtpk(s_[10], s_[11]);
        int b2 = cvtpk(s_[12], s_[13]), b3 = cvtpk(s_[14], s_[15]);
        plswap(a2, b2); plswap(a3, b3);
        union { int wd[4]; short8 s8; } u0_, u1_;
        u0_.wd[0] = a0; u0_.wd[1] = a1; u0_.wd[2] = b0; u0_.wd[3] = b1;
        u1_.wd[0] = a2; u1_.wd[1] = a3; u1_.wd[2] = b2; u1_.wd[3] = b3;

        // O += P @ V from LDS (R6-verified idx: slot = 4h + 2ks + hi)
        __builtin_amdgcn_s_setprio(1);
        #pragma unroll
        for (int n = 0; n < 2; ++n) {
            int rowv = n * 32 + l31;
            int base = rowv * 64;
            int sw = rowv & 7;
            short8 vf0 = *reinterpret_cast<const short8*>(&lV[cur][base + (((4 * h + 0 + hi) ^ sw) * 8)]);
            oacc[n] = MFMA32(u0_.s8, vf0, oacc[n]);
            short8 vf1 = *reinterpret_cast<const short8*>(&lV[cur][base + (((4 * h + 2 + hi) ^ sw) * 8)]);
            oacc[n] = MFMA32(u1_.s8, vf1, oacc[n]);
        }
        __builtin_amdgcn_s_setprio(0);
    };

    STAGE(0, p0);

    int cur = 0;
    for (int pt = p0; pt <= pe; ++pt) {
        if (pt < pe) {
            STAGE(cur ^ 1, pt + 1);
            asm volatile("s_waitcnt vmcnt(4)" ::: "memory");   // tile-pt loads landed
        } else {
            asm volatile("s_waitcnt vmcnt(0)" ::: "memory");
        }
        __builtin_amdgcn_sched_barrier(0);
        __builtin_amdgcn_s_barrier();
        __builtin_amdgcn_sched_barrier(0);

        if (pt <= jp) {
            const int T0 = 2 * pt, T1 = T0 + 1;
            HALF(cur, T0, 0);
            if (T1 <= j) HALF(cur, T1, 1);   // skip beyond-diagonal half
        }

        __builtin_amdgcn_s_barrier();   // readers done before next-iter overwrite
        cur ^= 1;
    }

    // ---- epilogue: atomically accumulate partial (O', l') (R12-verified) ----
    const int qrow0 = bh * SS + j * 32;
    atomicAdd(&lp[qrow0 + l31], lrow);
    #pragma unroll
    for (int n = 0; n < 2; ++n) {
        #pragma unroll
        for (int r = 0; r < 16; ++r) {
            int q = (r & 3) + 8 * (r >> 2) + 4 * hi;
            int d = n * 32 + l31;
            atomicAdd(&Op[(qrow0 + q) * 64 + d], oacc[n][r]);
        }
    }
}

// ---- normalize: AO[b,s,h*64+d] = Op[bh,s,d] / lp[bh,s] ----
__global__ __launch_bounds__(256) void norm_kernel(const float* __restrict__ Op,
                                                   const float* __restrict__ lp,
                                                   bf16* __restrict__ AO) {
    int idx = blockIdx.x * 256 + threadIdx.x;     // 0 .. 3145727
    int d = idx & 63, srow = idx >> 6;            // srow = bh*2048 + s
    int bh = srow >> 11, s = srow & 2047;
    int b = bh / SH, h = bh - b * SH;
    float v = Op[idx] / lp[srow];
    AO[(b * SS + s) * SD + h * 64 + d] = __float2bfloat16(v);
}

extern "C" void kernel_launch(void* const* d_in, const int* in_sizes, int n_in,
                              void* d_out, int out_size, void* d_ws, size_t ws_size,
                              hipStream_t stream) {
    const float* x  = (const float*)d_in[0];
    const float* wq = (const float*)d_in[1];
    const float* wk = (const float*)d_in[2];
    const float* wv = (const float*)d_in[3];
    const float* wo = (const float*)d_in[4];
    float* out = (float*)d_out;

    bf16* xb   = (bf16*)d_ws;              // reused as ao after gemm<0>
    bf16* wqkv = xb + SM * SD;
    bf16* wob  = wqkv + 3 * SD * SD;
    bf16* qkv  = wob + SD * SD;            // Q, K, V^T
    float* Op  = (float*)(qkv + 3 * BHSD); // 3,145,728 f32 partial O'
    float* lp  = Op + 3145728;             // 49,152 f32
    bf16* ao   = xb;

    hipMemsetAsync(Op, 0, (3145728 + SB * SH * SS) * sizeof(float), stream);

    cvt_all<<<3072 + 4 * 576, 256, 0, stream>>>(
        (const float4*)x, (const float4*)wq, (const float4*)wk,
        (const float4*)wv, (const float4*)wo,
        (uint64_t*)xb, (uint64_t*)wqkv, (uint64_t*)wob);

    gemm_bt<0><<<dim3(2304 / 128, SM / 128), 256, 0, stream>>>(xb, wqkv, (void*)qkv, SD);
    attn_kernel<<<960, 256, 0, stream>>>(qkv, qkv + BHSD, qkv + 2 * BHSD, Op, lp);
    norm_kernel<<<3145728 / 256, 256, 0, stream>>>(Op, lp, ao);
    gemm_bt<1><<<dim3(SD / 128, SM / 128), 256, 0, stream>>>(ao, wob, (void*)out, SD);
}